// Round 1
// baseline (1005.421 us; speedup 1.0000x reference)
//
#include <hip/hip_runtime.h>
#include <stdint.h>

#define KTOT 4507
#define POSTN 1000
#define ATOT 159882
#define NIMG 4
#define CAND_CAP 4096

// ---------- helpers ----------

// monotone float->uint mapping (total order preserving)
__device__ inline unsigned fmono(float f) {
    unsigned u = __float_as_uint(f);
    return (u & 0x80000000u) ? ~u : (u | 0x80000000u);
}
__device__ inline float fmono_inv(unsigned u) {
    unsigned b = (u & 0x80000000u) ? (u ^ 0x80000000u) : ~u;
    return __uint_as_float(b);
}

__device__ inline unsigned long long shfl_u64(unsigned long long v, int src) {
    int lo = __shfl((int)(unsigned)(v & 0xFFFFFFFFULL), src);
    int hi = __shfl((int)(unsigned)(v >> 32), src);
    return ((unsigned long long)(unsigned)hi << 32) | (unsigned)lo;
}

// exclusive prefix over all threads of a 1024-thread block.
// warpSums must be LDS int[>=16]. Contains __syncthreads -> call uniformly.
__device__ inline int blockExclScan(int v, int* warpSums) {
    int tid = threadIdx.x;
    int lane = tid & 63, wid = tid >> 6;
    int x = v;
#pragma unroll
    for (int d = 1; d < 64; d <<= 1) {
        int y = __shfl_up(x, d);
        if (lane >= d) x += y;
    }
    if (lane == 63) warpSums[wid] = x;
    __syncthreads();
    if (wid == 0) {
        int s = (lane < 16) ? warpSums[lane] : 0;
#pragma unroll
        for (int d = 1; d < 16; d <<= 1) {
            int y = __shfl_up(s, d);
            if (lane >= d) s += y;
        }
        if (lane < 16) warpSums[lane] = s;  // inclusive wave totals
    }
    __syncthreads();
    int wpre = (wid == 0) ? 0 : warpSums[wid - 1];
    return wpre + (x - v);
}

// ---------- stage A: per-(img,level) top-k, sorted (logit desc, idx asc) ----------

__global__ __launch_bounds__(1024) void topk_kernel(const float* __restrict__ obj,
                                                    int* __restrict__ selIdx,
                                                    float* __restrict__ selLogit) {
    __shared__ unsigned hist[4096];
    __shared__ unsigned long long cand[CAND_CAP];
    __shared__ int s_misc[32];
    __shared__ int s_cnt, s_bstar;

    const int lvlOff[5] = {0, 120000, 150000, 157500, 159375};
    const int lvlN[5]   = {120000, 30000, 7500, 1875, 507};
    const int ksel[5]   = {1000, 1000, 1000, 1000, 507};
    const int koff[5]   = {0, 1000, 2000, 3000, 4000};

    int img = blockIdx.x / 5, lvl = blockIdx.x % 5;
    int n = lvlN[lvl], k = ksel[lvl];
    const float* src = obj + (size_t)img * ATOT + lvlOff[lvl];
    int tid = threadIdx.x;

    for (int i = tid; i < 4096; i += 1024) hist[i] = 0u;
    if (tid == 0) s_cnt = 0;
    __syncthreads();

    for (int i = tid; i < n; i += 1024) {
        unsigned key = fmono(src[i]);
        atomicAdd(&hist[key >> 20], 1u);
    }
    __syncthreads();

    // exclusive-prefix over 4096 bins (blocked: thread t owns bins 4t..4t+3)
    unsigned c0 = hist[4 * tid + 0], c1 = hist[4 * tid + 1];
    unsigned c2 = hist[4 * tid + 2], c3 = hist[4 * tid + 3];
    int mysum = (int)(c0 + c1 + c2 + c3);
    int excl = blockExclScan(mysum, s_misc);
    int target = n - k;  // number of elements strictly below the boundary bin region
    {
        int P = excl;
        if ((int)c0 > 0 && P <= target && target < P + (int)c0) s_bstar = 4 * tid + 0;
        P += (int)c0;
        if ((int)c1 > 0 && P <= target && target < P + (int)c1) s_bstar = 4 * tid + 1;
        P += (int)c1;
        if ((int)c2 > 0 && P <= target && target < P + (int)c2) s_bstar = 4 * tid + 2;
        P += (int)c2;
        if ((int)c3 > 0 && P <= target && target < P + (int)c3) s_bstar = 4 * tid + 3;
    }
    __syncthreads();
    int bstar = s_bstar;

    // gather candidates (bins >= boundary bin): count in [k, k+bin_width_count)
    for (int i = tid; i < n; i += 1024) {
        unsigned key = fmono(src[i]);
        if ((int)(key >> 20) >= bstar) {
            int pos = atomicAdd(&s_cnt, 1);
            if (pos < CAND_CAP)
                cand[pos] = ((unsigned long long)key << 32) | (unsigned)(~(unsigned)i);
        }
    }
    __syncthreads();
    int m = s_cnt; if (m > CAND_CAP) m = CAND_CAP;
    for (int i = tid; i < CAND_CAP; i += 1024)
        if (i >= m) cand[i] = 0ULL;
    __syncthreads();

    // bitonic ascending sort of CAND_CAP u64 keys
    for (unsigned kk = 2; kk <= CAND_CAP; kk <<= 1) {
        for (unsigned j = kk >> 1; j > 0; j >>= 1) {
            for (unsigned i = (unsigned)tid; i < CAND_CAP; i += 1024) {
                unsigned ixj = i ^ j;
                if (ixj > i) {
                    unsigned long long a = cand[i], b = cand[ixj];
                    bool up = ((i & kk) == 0);
                    if ((a > b) == up) { cand[i] = b; cand[ixj] = a; }
                }
            }
            __syncthreads();
        }
    }

    // emit top-k descending (= (logit desc, idx asc), matching lax.top_k ties)
    for (int r = tid; r < k; r += 1024) {
        unsigned long long key = cand[CAND_CAP - 1 - r];
        unsigned hi = (unsigned)(key >> 32);
        int li = (int)(~(unsigned)key);
        selIdx[(size_t)img * KTOT + koff[lvl] + r] = lvlOff[lvl] + li;
        selLogit[(size_t)img * KTOT + koff[lvl] + r] = fmono_inv(hi);
    }
}

// ---------- stage B: decode + score + global rank (per image) ----------

__global__ __launch_bounds__(1024) void decode_sort_kernel(
    const float* __restrict__ deltas, const float* __restrict__ anchors,
    const int* __restrict__ selIdx, const float* __restrict__ selLogit,
    float* __restrict__ sx1, float* __restrict__ sy1, float* __restrict__ sx2,
    float* __restrict__ sy2, float* __restrict__ sscore,
    int* __restrict__ slvl, int* __restrict__ svalid) {
    __shared__ unsigned long long keyAll[KTOT];
    __shared__ unsigned long long buf[1024];

    const int koff[5] = {0, 1000, 2000, 3000, 4000};
    const int ksel[5] = {1000, 1000, 1000, 1000, 507};

    int img = blockIdx.x;
    int tid = threadIdx.x;

    float mx1[5], my1[5], mx2[5], my2[5], msc[5];
    int mlvl[5], mval[5];
    unsigned long long mkey[5];

#pragma unroll
    for (int c = 0; c < 5; c++) {
        int p = tid + c * 1024;
        if (p < KTOT) {
            int lvl = (p < 1000) ? 0 : (p < 2000) ? 1 : (p < 3000) ? 2 : (p < 4000) ? 3 : 4;
            int idx = selIdx[(size_t)img * KTOT + p];
            float logit = selLogit[(size_t)img * KTOT + p];
            // sigmoid: 1/(1+exp(-x)), exp computed in f64 then rounded (≈ correctly rounded f32 exp)
            float ef = (float)exp(-(double)logit);
            float s = 1.0f / __fadd_rn(1.0f, ef);
            // decode (torchvision BoxCoder, weights=1), strictly no FMA contraction
            float a0 = anchors[(size_t)idx * 4 + 0], a1 = anchors[(size_t)idx * 4 + 1];
            float a2 = anchors[(size_t)idx * 4 + 2], a3 = anchors[(size_t)idx * 4 + 3];
            const float* dp = deltas + ((size_t)img * ATOT + idx) * 4;
            float dx = dp[0], dy = dp[1];
            const float BCLIP = 4.135166556742356f;  // log(1000/16)
            float dw = fminf(dp[2], BCLIP), dh = fminf(dp[3], BCLIP);
            float wa = __fsub_rn(a2, a0), ha = __fsub_rn(a3, a1);
            float cxa = __fadd_rn(a0, __fmul_rn(0.5f, wa));
            float cya = __fadd_rn(a1, __fmul_rn(0.5f, ha));
            float cx = __fadd_rn(__fmul_rn(dx, wa), cxa);
            float cy = __fadd_rn(__fmul_rn(dy, ha), cya);
            float w = __fmul_rn((float)exp((double)dw), wa);
            float h = __fmul_rn((float)exp((double)dh), ha);
            float x1 = __fsub_rn(cx, __fmul_rn(0.5f, w));
            float y1 = __fsub_rn(cy, __fmul_rn(0.5f, h));
            float x2 = __fadd_rn(cx, __fmul_rn(0.5f, w));
            float y2 = __fadd_rn(cy, __fmul_rn(0.5f, h));
            x1 = fminf(fmaxf(x1, 0.0f), 800.0f);
            y1 = fminf(fmaxf(y1, 0.0f), 800.0f);
            x2 = fminf(fmaxf(x2, 0.0f), 800.0f);
            y2 = fminf(fmaxf(y2, 0.0f), 800.0f);
            int valid = (__fsub_rn(x2, x1) >= 0.001f) && (__fsub_rn(y2, y1) >= 0.001f) &&
                        (s >= 0.0f);
            unsigned hi = valid ? fmono(s) : 0u;  // invalid == -inf score in ref sort
            unsigned long long key = ((unsigned long long)hi << 32) | (unsigned)(~(unsigned)p);
            keyAll[p] = key;
            mx1[c] = x1; my1[c] = y1; mx2[c] = x2; my2[c] = y2; msc[c] = s;
            mlvl[c] = lvl; mval[c] = valid; mkey[c] = key;
        }
    }
    __syncthreads();

    // sort each level's keys descending in place (1024-wide bitonic, pad=0)
    for (int lvl = 0; lvl < 5; lvl++) {
        int base = koff[lvl], kn = ksel[lvl];
        buf[tid] = (tid < kn) ? keyAll[base + tid] : 0ULL;
        __syncthreads();
        for (unsigned kk = 2; kk <= 1024; kk <<= 1) {
            for (unsigned j = kk >> 1; j > 0; j >>= 1) {
                unsigned i = (unsigned)tid, ixj = i ^ j;
                if (ixj > i) {
                    unsigned long long a = buf[i], b = buf[ixj];
                    bool up = ((i & kk) == 0);
                    if ((a > b) == up) { buf[i] = b; buf[ixj] = a; }
                }
                __syncthreads();
            }
        }
        if (tid < kn) keyAll[base + tid] = buf[1023 - tid];  // descending, pads dropped
        __syncthreads();
    }

    // global rank of each item = sum over levels of (# keys > mine); scatter records
#pragma unroll
    for (int c = 0; c < 5; c++) {
        int p = tid + c * 1024;
        if (p < KTOT) {
            unsigned long long key = mkey[c];
            int rank = 0;
#pragma unroll
            for (int lvl = 0; lvl < 5; lvl++) {
                int base = koff[lvl];
                int lo = 0, hi2 = ksel[lvl];
                while (lo < hi2) {
                    int mid = (lo + hi2) >> 1;
                    if (keyAll[base + mid] > key) lo = mid + 1; else hi2 = mid;
                }
                rank += lo;
            }
            size_t o = (size_t)img * KTOT + rank;
            sx1[o] = mx1[c]; sy1[o] = my1[c]; sx2[o] = mx2[c]; sy2[o] = my2[c];
            sscore[o] = msc[c]; slvl[o] = mlvl[c]; svalid[o] = mval[c];
        }
    }
}

// ---------- stage C: per-(img,level) NMS (mask build + sequential wave scan) ----------

__global__ __launch_bounds__(1024) void nms_kernel(
    const float* __restrict__ sx1, const float* __restrict__ sy1,
    const float* __restrict__ sx2, const float* __restrict__ sy2,
    const int* __restrict__ slvl, const int* __restrict__ svalid,
    unsigned long long* __restrict__ maskBuf, int* __restrict__ gkeep) {
    __shared__ float lx1[1000], ly1[1000], lx2[1000], ly2[1000], lar[1000];
    __shared__ int lgpos[1000];
    __shared__ int s_warp[32];
    __shared__ int s_m;

    const int ksel[5] = {1000, 1000, 1000, 1000, 507};
    const int wpl[5] = {16, 16, 16, 16, 8};

    int img = blockIdx.x / 5, lvl = blockIdx.x % 5;
    int tid = threadIdx.x;

    size_t mOff = (size_t)img * 68056;  // 4*1000*16 + 507*8
    for (int l = 0; l < lvl; l++) mOff += (size_t)ksel[l] * wpl[l];
    unsigned long long* M = maskBuf + mOff;
    int Wa = wpl[lvl];

    // stable compaction of this level's VALID items in global-sorted order (blocked dist)
    int myFlag[5];
    int cnt = 0;
    int start = tid * 5;
#pragma unroll
    for (int c = 0; c < 5; c++) {
        int j = start + c;
        int f = 0;
        if (j < KTOT) {
            size_t o = (size_t)img * KTOT + j;
            f = (slvl[o] == lvl) && svalid[o];
        }
        myFlag[c] = f;
        cnt += f;
    }
    int pos = blockExclScan(cnt, s_warp);
    float lf = 1000.0f * (float)lvl;
#pragma unroll
    for (int c = 0; c < 5; c++) {
        if (myFlag[c]) {
            int j = start + c;
            size_t o = (size_t)img * KTOT + j;
            float ox1 = __fadd_rn(sx1[o], lf);
            float oy1 = __fadd_rn(sy1[o], lf);
            float ox2 = __fadd_rn(sx2[o], lf);
            float oy2 = __fadd_rn(sy2[o], lf);
            lx1[pos] = ox1; ly1[pos] = oy1; lx2[pos] = ox2; ly2[pos] = oy2;
            lar[pos] = __fmul_rn(__fsub_rn(ox2, ox1), __fsub_rn(oy2, oy1));
            lgpos[pos] = j;
            pos++;
        }
    }
    if (tid == 1023) s_m = pos;  // last thread's excl+cnt == total
    __syncthreads();
    int m = s_m;
    int W = (m + 63) >> 6;

    // pairwise suppression bitmask (only j > i bits), rows strided by Wa in ws
    int tasks = m * W;
    for (int t = tid; t < tasks; t += 1024) {
        int i = t / W, w = t - i * W;
        float ax1 = lx1[i], ay1 = ly1[i], ax2 = lx2[i], ay2 = ly2[i], aar = lar[i];
        unsigned long long bits = 0ULL;
        int jbase = w * 64;
        int jend = m < jbase + 64 ? m : jbase + 64;
        int j0 = jbase > i + 1 ? jbase : i + 1;
        for (int j = j0; j < jend; j++) {
            float ltx = fmaxf(ax1, lx1[j]);
            float lty = fmaxf(ay1, ly1[j]);
            float rbx = fminf(ax2, lx2[j]);
            float rby = fminf(ay2, ly2[j]);
            float wq = fmaxf(__fsub_rn(rbx, ltx), 0.0f);
            float hq = fmaxf(__fsub_rn(rby, lty), 0.0f);
            float inter = __fmul_rn(wq, hq);
            float uni = __fsub_rn(__fadd_rn(aar, lar[j]), inter);
            float iou = inter / uni;
            if (iou > 0.7f) bits |= 1ULL << (j - jbase);
        }
        M[(size_t)i * Wa + w] = bits;
    }
    __syncthreads();

    // sequential greedy scan: wave 0, lane w owns removal word w; 8-deep prefetch
    if (tid < 64) {
        int lane = tid;
        unsigned long long remv = 0ULL;
        bool own = (lane < W);
        const unsigned long long* Mr = M + lane;
        unsigned long long pf[8];
#pragma unroll
        for (int r = 0; r < 8; r++) pf[r] = (own && r < m) ? Mr[(size_t)r * Wa] : 0ULL;
        int nch = (m + 7) >> 3;
        for (int cchunk = 0; cchunk < nch; cchunk++) {
            unsigned long long cur[8];
#pragma unroll
            for (int r = 0; r < 8; r++) cur[r] = pf[r];
            int nb = (cchunk + 1) * 8;
#pragma unroll
            for (int r = 0; r < 8; r++) {
                int i2 = nb + r;
                pf[r] = (own && i2 < m) ? Mr[(size_t)i2 * Wa] : 0ULL;
            }
#pragma unroll
            for (int r = 0; r < 8; r++) {
                int i = cchunk * 8 + r;
                if (i < m) {
                    unsigned long long rw = shfl_u64(remv, i >> 6);
                    bool alive = ((rw >> (i & 63)) & 1ULL) == 0ULL;
                    if (alive) remv |= cur[r];
                    if (lane == 0) gkeep[(size_t)img * KTOT + lgpos[i]] = alive ? 1 : 0;
                }
            }
        }
    }
}

// ---------- stage D: global rank of keeps + scatter output rows ----------

__global__ __launch_bounds__(1024) void out_kernel(
    const float* __restrict__ sx1, const float* __restrict__ sy1,
    const float* __restrict__ sx2, const float* __restrict__ sy2,
    const float* __restrict__ sscore, const int* __restrict__ gkeep,
    float* __restrict__ out) {
    __shared__ int s_warp[32];
    int img = blockIdx.x, tid = threadIdx.x;
    int myk[5];
    int cnt = 0;
    int start = tid * 5;
#pragma unroll
    for (int c = 0; c < 5; c++) {
        int j = start + c;
        int f = (j < KTOT) ? gkeep[(size_t)img * KTOT + j] : 0;
        myk[c] = f;
        cnt += f;
    }
    int rank = blockExclScan(cnt, s_warp);
#pragma unroll
    for (int c = 0; c < 5; c++) {
        if (myk[c]) {
            if (rank < POSTN) {
                int j = start + c;
                size_t o = (size_t)img * KTOT + j;
                float* dst = out + ((size_t)img * POSTN + rank) * 5;
                dst[0] = sx1[o]; dst[1] = sy1[o]; dst[2] = sx2[o]; dst[3] = sy2[o];
                dst[4] = sscore[o];
            }
            rank++;
        }
    }
}

// ---------- host ----------

extern "C" void kernel_launch(void* const* d_in, const int* in_sizes, int n_in,
                              void* d_out, int out_size, void* d_ws, size_t ws_size,
                              hipStream_t stream) {
    const float* obj = (const float*)d_in[0];
    const float* deltas = (const float*)d_in[1];
    const float* anchors = (const float*)d_in[2];
    float* out = (float*)d_out;

    char* ws = (char*)d_ws;
    size_t off = 0;
    auto alloc = [&](size_t bytes) {
        size_t o = off;
        off += (bytes + 255) & ~(size_t)255;
        return o;
    };
    int* selIdx = (int*)(ws + alloc((size_t)NIMG * KTOT * 4));
    float* selLogit = (float*)(ws + alloc((size_t)NIMG * KTOT * 4));
    float* sx1 = (float*)(ws + alloc((size_t)NIMG * KTOT * 4));
    float* sy1 = (float*)(ws + alloc((size_t)NIMG * KTOT * 4));
    float* sx2 = (float*)(ws + alloc((size_t)NIMG * KTOT * 4));
    float* sy2 = (float*)(ws + alloc((size_t)NIMG * KTOT * 4));
    float* sscore = (float*)(ws + alloc((size_t)NIMG * KTOT * 4));
    int* slvl = (int*)(ws + alloc((size_t)NIMG * KTOT * 4));
    int* svalid = (int*)(ws + alloc((size_t)NIMG * KTOT * 4));
    int* gkeep = (int*)(ws + alloc((size_t)NIMG * KTOT * 4));
    unsigned long long* maskBuf =
        (unsigned long long*)(ws + alloc((size_t)NIMG * 68056ULL * 8));

    hipMemsetAsync(gkeep, 0, (size_t)NIMG * KTOT * 4, stream);
    hipMemsetAsync(d_out, 0, (size_t)out_size * 4, stream);

    topk_kernel<<<dim3(NIMG * 5), dim3(1024), 0, stream>>>(obj, selIdx, selLogit);
    decode_sort_kernel<<<dim3(NIMG), dim3(1024), 0, stream>>>(
        deltas, anchors, selIdx, selLogit, sx1, sy1, sx2, sy2, sscore, slvl, svalid);
    nms_kernel<<<dim3(NIMG * 5), dim3(1024), 0, stream>>>(sx1, sy1, sx2, sy2, slvl, svalid,
                                                          maskBuf, gkeep);
    out_kernel<<<dim3(NIMG), dim3(1024), 0, stream>>>(sx1, sy1, sx2, sy2, sscore, gkeep, out);
}

// Round 2
// 358.981 us; speedup vs baseline: 2.8008x; 2.8008x over previous
//
#include <hip/hip_runtime.h>
#include <stdint.h>

#define KTOT 4507
#define POSTN 1000
#define ATOT 159882
#define NIMG 4
#define CAND_CAP 4096
#define SLOTCAP 5000  // per-image compact capacity (koff spacing = lvl*1000)

// ---------- helpers ----------

__device__ inline unsigned fmono(float f) {
    unsigned u = __float_as_uint(f);
    return (u & 0x80000000u) ? ~u : (u | 0x80000000u);
}
__device__ inline float fmono_inv(unsigned u) {
    unsigned b = (u & 0x80000000u) ? (u ^ 0x80000000u) : ~u;
    return __uint_as_float(b);
}

__device__ inline unsigned long long shfl_u64(unsigned long long v, int src) {
    int lo = __shfl((int)(unsigned)(v & 0xFFFFFFFFULL), src);
    int hi = __shfl((int)(unsigned)(v >> 32), src);
    return ((unsigned long long)(unsigned)hi << 32) | (unsigned)lo;
}

// exclusive prefix over a 1024-thread block; warpSums = LDS int[>=16]; call uniformly
__device__ inline int blockExclScan(int v, int* warpSums) {
    int tid = threadIdx.x;
    int lane = tid & 63, wid = tid >> 6;
    int x = v;
#pragma unroll
    for (int d = 1; d < 64; d <<= 1) {
        int y = __shfl_up(x, d);
        if (lane >= d) x += y;
    }
    if (lane == 63) warpSums[wid] = x;
    __syncthreads();
    if (wid == 0) {
        int s = (lane < 16) ? warpSums[lane] : 0;
#pragma unroll
        for (int d = 1; d < 16; d <<= 1) {
            int y = __shfl_up(s, d);
            if (lane >= d) s += y;
        }
        if (lane < 16) warpSums[lane] = s;
    }
    __syncthreads();
    int wpre = (wid == 0) ? 0 : warpSums[wid - 1];
    return wpre + (x - v);
}

// ---------- stage A: per-(img,level) top-k, emitted in (logit desc, idx asc) order ----------

__global__ __launch_bounds__(1024) void topk_kernel(const float* __restrict__ obj,
                                                    int* __restrict__ selIdx,
                                                    float* __restrict__ selLogit) {
    __shared__ unsigned hist[4096];
    __shared__ unsigned long long cand[CAND_CAP];
    __shared__ int s_misc[32];
    __shared__ int s_cnt, s_bstar;

    const int lvlOff[5] = {0, 120000, 150000, 157500, 159375};
    const int lvlN[5]   = {120000, 30000, 7500, 1875, 507};

    int img = blockIdx.x / 5, lvl = blockIdx.x % 5;
    int n = lvlN[lvl];
    int k = (lvl == 4) ? 507 : 1000;
    int koff = lvl * 1000;
    const float* src = obj + (size_t)img * ATOT + lvlOff[lvl];
    int tid = threadIdx.x;

    for (int i = tid; i < 4096; i += 1024) hist[i] = 0u;
    if (tid == 0) s_cnt = 0;
    __syncthreads();

    for (int i = tid; i < n; i += 1024) {
        unsigned key = fmono(src[i]);
        atomicAdd(&hist[key >> 20], 1u);
    }
    __syncthreads();

    unsigned c0 = hist[4 * tid + 0], c1 = hist[4 * tid + 1];
    unsigned c2 = hist[4 * tid + 2], c3 = hist[4 * tid + 3];
    int mysum = (int)(c0 + c1 + c2 + c3);
    int excl = blockExclScan(mysum, s_misc);
    int target = n - k;
    {
        int P = excl;
        if ((int)c0 > 0 && P <= target && target < P + (int)c0) s_bstar = 4 * tid + 0;
        P += (int)c0;
        if ((int)c1 > 0 && P <= target && target < P + (int)c1) s_bstar = 4 * tid + 1;
        P += (int)c1;
        if ((int)c2 > 0 && P <= target && target < P + (int)c2) s_bstar = 4 * tid + 2;
        P += (int)c2;
        if ((int)c3 > 0 && P <= target && target < P + (int)c3) s_bstar = 4 * tid + 3;
    }
    __syncthreads();
    int bstar = s_bstar;

    for (int i = tid; i < n; i += 1024) {
        unsigned key = fmono(src[i]);
        if ((int)(key >> 20) >= bstar) {
            int pos = atomicAdd(&s_cnt, 1);
            if (pos < CAND_CAP)
                cand[pos] = ((unsigned long long)key << 32) | (unsigned)(~(unsigned)i);
        }
    }
    __syncthreads();
    int m = s_cnt; if (m > CAND_CAP) m = CAND_CAP;
    for (int i = tid; i < CAND_CAP; i += 1024)
        if (i >= m) cand[i] = 0ULL;
    __syncthreads();

    for (unsigned kk = 2; kk <= CAND_CAP; kk <<= 1) {
        for (unsigned j = kk >> 1; j > 0; j >>= 1) {
            for (unsigned i = (unsigned)tid; i < CAND_CAP; i += 1024) {
                unsigned ixj = i ^ j;
                if (ixj > i) {
                    unsigned long long a = cand[i], b = cand[ixj];
                    bool up = ((i & kk) == 0);
                    if ((a > b) == up) { cand[i] = b; cand[ixj] = a; }
                }
            }
            __syncthreads();
        }
    }

    for (int r = tid; r < k; r += 1024) {
        unsigned long long key = cand[CAND_CAP - 1 - r];
        unsigned hi = (unsigned)(key >> 32);
        int li = (int)(~(unsigned)key);
        selIdx[(size_t)img * KTOT + koff + r] = lvlOff[lvl] + li;
        selLogit[(size_t)img * KTOT + koff + r] = fmono_inv(hi);
    }
}

// ---------- stage B: decode + score + valid, in slot (level-major top-k) layout ----------

__global__ __launch_bounds__(256) void decode_kernel(
    const float* __restrict__ deltas, const float* __restrict__ anchors,
    const int* __restrict__ selIdx, const float* __restrict__ selLogit,
    float* __restrict__ sx1, float* __restrict__ sy1, float* __restrict__ sx2,
    float* __restrict__ sy2, float* __restrict__ sscore, int* __restrict__ svalid) {
    int p = blockIdx.x * 256 + threadIdx.x;
    int img = blockIdx.y;
    if (p >= KTOT) return;
    size_t o = (size_t)img * KTOT + p;
    int idx = selIdx[o];
    float logit = selLogit[o];
    float ef = (float)exp(-(double)logit);
    float s = 1.0f / __fadd_rn(1.0f, ef);
    float a0 = anchors[(size_t)idx * 4 + 0], a1 = anchors[(size_t)idx * 4 + 1];
    float a2 = anchors[(size_t)idx * 4 + 2], a3 = anchors[(size_t)idx * 4 + 3];
    const float* dp = deltas + ((size_t)img * ATOT + idx) * 4;
    float dx = dp[0], dy = dp[1];
    const float BCLIP = 4.135166556742356f;  // log(1000/16)
    float dw = fminf(dp[2], BCLIP), dh = fminf(dp[3], BCLIP);
    float wa = __fsub_rn(a2, a0), ha = __fsub_rn(a3, a1);
    float cxa = __fadd_rn(a0, __fmul_rn(0.5f, wa));
    float cya = __fadd_rn(a1, __fmul_rn(0.5f, ha));
    float cx = __fadd_rn(__fmul_rn(dx, wa), cxa);
    float cy = __fadd_rn(__fmul_rn(dy, ha), cya);
    float w = __fmul_rn((float)exp((double)dw), wa);
    float h = __fmul_rn((float)exp((double)dh), ha);
    float x1 = __fsub_rn(cx, __fmul_rn(0.5f, w));
    float y1 = __fsub_rn(cy, __fmul_rn(0.5f, h));
    float x2 = __fadd_rn(cx, __fmul_rn(0.5f, w));
    float y2 = __fadd_rn(cy, __fmul_rn(0.5f, h));
    x1 = fminf(fmaxf(x1, 0.0f), 800.0f);
    y1 = fminf(fmaxf(y1, 0.0f), 800.0f);
    x2 = fminf(fmaxf(x2, 0.0f), 800.0f);
    y2 = fminf(fmaxf(y2, 0.0f), 800.0f);
    int valid = (__fsub_rn(x2, x1) >= 0.001f) && (__fsub_rn(y2, y1) >= 0.001f) && (s >= 0.0f);
    sx1[o] = x1; sy1[o] = y1; sx2[o] = x2; sy2[o] = y2;
    sscore[o] = s; svalid[o] = valid;
}

// ---------- stage C1: per-(img,level) compaction of valid slots (slot order = sorted order) ----------

__global__ __launch_bounds__(1024) void compact_kernel(
    const float* __restrict__ sx1, const float* __restrict__ sy1,
    const float* __restrict__ sx2, const float* __restrict__ sy2,
    const float* __restrict__ sscore, const int* __restrict__ svalid,
    float* __restrict__ cx1, float* __restrict__ cy1, float* __restrict__ cx2,
    float* __restrict__ cy2, float* __restrict__ car,
    unsigned long long* __restrict__ ckey, int* __restrict__ cslot, int* __restrict__ cm) {
    __shared__ int s_warp[32];
    int img = blockIdx.x / 5, lvl = blockIdx.x % 5;
    int kn = (lvl == 4) ? 507 : 1000;
    int koff = lvl * 1000;
    int tid = threadIdx.x;
    int r = tid;
    size_t o = (size_t)img * KTOT + koff + r;
    int flag = (r < kn) ? svalid[o] : 0;
    int pos = blockExclScan(flag, s_warp);
    if (flag) {
        float lf = 1000.0f * (float)lvl;
        size_t cb = (size_t)img * SLOTCAP + koff + pos;
        float ox1 = __fadd_rn(sx1[o], lf);
        float oy1 = __fadd_rn(sy1[o], lf);
        float ox2 = __fadd_rn(sx2[o], lf);
        float oy2 = __fadd_rn(sy2[o], lf);
        cx1[cb] = ox1; cy1[cb] = oy1; cx2[cb] = ox2; cy2[cb] = oy2;
        car[cb] = __fmul_rn(__fsub_rn(ox2, ox1), __fsub_rn(oy2, oy1));
        int p = koff + r;
        ckey[cb] = ((unsigned long long)fmono(sscore[o]) << 32) | (unsigned)(~(unsigned)p);
        cslot[cb] = p;
    }
    if (tid == 1023) cm[img * 5 + lvl] = pos + flag;
}

// ---------- stage C2: suppression-mask build, one wave per 64x64 tile, ballot form ----------

__global__ __launch_bounds__(512) void mask_kernel(
    const float* __restrict__ cx1, const float* __restrict__ cy1,
    const float* __restrict__ cx2, const float* __restrict__ cy2,
    const float* __restrict__ car, const int* __restrict__ cm,
    unsigned long long* __restrict__ maskBuf) {
    __shared__ float lx1[1000], ly1[1000], lx2[1000], ly2[1000], lar[1000];
    int iq = blockIdx.y;
    int img = iq / 5, lvl = iq % 5;
    int m = cm[img * 5 + lvl];
    int W = (m + 63) >> 6;
    int T = (W * (W + 1)) >> 1;  // one task per lower-triangular 64x64 tile (w, c<=w)
    int tbase = blockIdx.x * 8;
    if (tbase >= T) return;

    size_t cb0 = (size_t)img * SLOTCAP + lvl * 1000;
    for (int q = threadIdx.x; q < m; q += 512) {
        lx1[q] = cx1[cb0 + q]; ly1[q] = cy1[cb0 + q];
        lx2[q] = cx2[cb0 + q]; ly2[q] = cy2[cb0 + q];
        lar[q] = car[cb0 + q];
    }
    __syncthreads();

    int wv = threadIdx.x >> 6, lane = threadIdx.x & 63;
    int t = tbase + wv;
    if (t >= T) return;
    int w = (int)((sqrtf(8.0f * (float)t + 1.0f) - 1.0f) * 0.5f);
    while (((w + 1) * (w + 2)) / 2 <= t) w++;
    while ((w * (w + 1)) / 2 > t) w--;
    int c = t - ((w * (w + 1)) >> 1);

    size_t mOff = (size_t)img * 68056 + (size_t)lvl * 16000;
    int Wa = (lvl == 4) ? 8 : 16;
    unsigned long long* M = maskBuf + mOff;

    int j = (w << 6) + lane;
    bool jv = j < m;
    float jx1 = jv ? lx1[j] : 0.f, jy1 = jv ? ly1[j] : 0.f;
    float jx2 = jv ? lx2[j] : 0.f, jy2 = jv ? ly2[j] : 0.f;
    float jar = jv ? lar[j] : 0.f;

    unsigned long long myword = 0ULL;
    int i0 = c << 6, i1 = min(i0 + 64, m);
    for (int i = i0; i < i1; i++) {
        float ix1 = lx1[i], iy1 = ly1[i], ix2 = lx2[i], iy2 = ly2[i], iar = lar[i];
        float ltx = fmaxf(ix1, jx1);
        float lty = fmaxf(iy1, jy1);
        float rbx = fminf(ix2, jx2);
        float rby = fminf(iy2, jy2);
        float wq = fmaxf(__fsub_rn(rbx, ltx), 0.0f);
        float hq = fmaxf(__fsub_rn(rby, lty), 0.0f);
        float inter = __fmul_rn(wq, hq);
        float uni = __fsub_rn(__fadd_rn(iar, jar), inter);
        float iou = inter / uni;  // keep IEEE div: decisions must match reference exactly
        bool bit = jv && (j > i) && (iou > 0.7f);
        unsigned long long bal = __ballot(bit);
        if (lane == (i & 63)) myword = bal;
    }
    int irow = i0 + lane;
    if (irow < i1) M[(size_t)irow * Wa + w] = myword;
}

// ---------- stage C3: sequential greedy scan + kept-list compaction ----------

__global__ __launch_bounds__(1024) void scan_kernel(
    const unsigned long long* __restrict__ maskBuf,
    const unsigned long long* __restrict__ ckey, const int* __restrict__ cslot,
    const int* __restrict__ cm,
    unsigned long long* __restrict__ keptKey, int* __restrict__ keptSlot,
    int* __restrict__ keptCnt) {
    __shared__ int lkeep[1000];
    __shared__ int s_warp[32];
    int img = blockIdx.x / 5, lvl = blockIdx.x % 5;
    int m = cm[img * 5 + lvl];
    int W = (m + 63) >> 6;
    int Wa = (lvl == 4) ? 8 : 16;
    const unsigned long long* M = maskBuf + (size_t)img * 68056 + (size_t)lvl * 16000;
    int tid = threadIdx.x;
    int koff = lvl * 1000;

    if (tid < 64) {
        int lane = tid;
        bool own = lane < W;
        int mlim = min(m, (lane + 1) << 6);  // rows beyond this have no bits for this word
        const unsigned long long* Mr = M + lane;
        unsigned long long remv = 0ULL;
        unsigned long long pf[16];
#pragma unroll
        for (int r2 = 0; r2 < 16; r2++)
            pf[r2] = (own && r2 < mlim) ? Mr[(size_t)r2 * Wa] : 0ULL;
        int nch = (m + 15) >> 4;
        for (int ch = 0; ch < nch; ch++) {
            unsigned long long cur[16];
#pragma unroll
            for (int r2 = 0; r2 < 16; r2++) cur[r2] = pf[r2];
            int nb = (ch + 1) << 4;
#pragma unroll
            for (int r2 = 0; r2 < 16; r2++) {
                int i2 = nb + r2;
                pf[r2] = (own && i2 < mlim) ? Mr[(size_t)i2 * Wa] : 0ULL;
            }
#pragma unroll
            for (int r2 = 0; r2 < 16; r2++) {
                int i = (ch << 4) + r2;
                if (i < m) {
                    unsigned long long rw = shfl_u64(remv, i >> 6);
                    bool alive = ((rw >> (i & 63)) & 1ULL) == 0ULL;
                    if (alive) remv |= cur[r2];
                    if (lane == 0) lkeep[i] = alive ? 1 : 0;
                }
            }
        }
    }
    __syncthreads();

    int r = tid;
    int flag = (r < m) ? lkeep[r] : 0;
    int pos = blockExclScan(flag, s_warp);
    if (flag) {
        size_t cb = (size_t)img * SLOTCAP + koff + r;
        size_t kb = (size_t)img * KTOT + koff + pos;
        keptKey[kb] = ckey[cb];
        keptSlot[kb] = cslot[cb];
    }
    if (tid == 1023) keptCnt[img * 5 + lvl] = pos + flag;
}

// ---------- stage D: global rank of kept items via 5-list binary search + output ----------

__global__ __launch_bounds__(1024) void out_kernel(
    const float* __restrict__ sx1, const float* __restrict__ sy1,
    const float* __restrict__ sx2, const float* __restrict__ sy2,
    const float* __restrict__ sscore,
    const unsigned long long* __restrict__ keptKey, const int* __restrict__ keptSlot,
    const int* __restrict__ keptCnt, float* __restrict__ out) {
    __shared__ unsigned long long kkey[KTOT];
    __shared__ int s_cnt[5];
    int img = blockIdx.x, tid = threadIdx.x;
    if (tid < 5) s_cnt[tid] = keptCnt[img * 5 + tid];
    __syncthreads();

    for (int lvl = 0; lvl < 5; lvl++) {
        int Kc = s_cnt[lvl];
        int koff = lvl * 1000;
        size_t kb = (size_t)img * KTOT + koff;
        for (int q = tid; q < Kc; q += 1024) kkey[koff + q] = keptKey[kb + q];
    }
    __syncthreads();

    int tK = s_cnt[0] + s_cnt[1] + s_cnt[2] + s_cnt[3] + s_cnt[4];

    for (int lvl = 0; lvl < 5; lvl++) {
        int Kc = s_cnt[lvl];
        int koff = lvl * 1000;
        for (int q = tid; q < Kc; q += 1024) {
            unsigned long long key = kkey[koff + q];
            int rank = q;  // own list: q keys strictly greater (desc, distinct)
#pragma unroll
            for (int ol = 0; ol < 5; ol++) {
                if (ol == lvl) continue;
                int lo = 0, hi = s_cnt[ol], base = ol * 1000;
                while (lo < hi) {
                    int mid = (lo + hi) >> 1;
                    if (kkey[base + mid] > key) lo = mid + 1; else hi = mid;
                }
                rank += lo;
            }
            if (rank < POSTN) {
                int slot = keptSlot[(size_t)img * KTOT + koff + q];
                size_t o = (size_t)img * KTOT + slot;
                float* dst = out + ((size_t)img * POSTN + rank) * 5;
                dst[0] = sx1[o]; dst[1] = sy1[o]; dst[2] = sx2[o]; dst[3] = sy2[o];
                dst[4] = sscore[o];
            }
        }
    }

    int z0 = tK < POSTN ? tK : POSTN;
    int nz = (POSTN - z0) * 5;
    float* ob = out + (size_t)img * POSTN * 5 + (size_t)z0 * 5;
    for (int u = tid; u < nz; u += 1024) ob[u] = 0.f;
}

// ---------- host ----------

extern "C" void kernel_launch(void* const* d_in, const int* in_sizes, int n_in,
                              void* d_out, int out_size, void* d_ws, size_t ws_size,
                              hipStream_t stream) {
    const float* obj = (const float*)d_in[0];
    const float* deltas = (const float*)d_in[1];
    const float* anchors = (const float*)d_in[2];
    float* out = (float*)d_out;

    char* ws = (char*)d_ws;
    size_t off = 0;
    auto alloc = [&](size_t bytes) {
        size_t o = off;
        off += (bytes + 255) & ~(size_t)255;
        return o;
    };
    int* selIdx = (int*)(ws + alloc((size_t)NIMG * KTOT * 4));
    float* selLogit = (float*)(ws + alloc((size_t)NIMG * KTOT * 4));
    float* sx1 = (float*)(ws + alloc((size_t)NIMG * KTOT * 4));
    float* sy1 = (float*)(ws + alloc((size_t)NIMG * KTOT * 4));
    float* sx2 = (float*)(ws + alloc((size_t)NIMG * KTOT * 4));
    float* sy2 = (float*)(ws + alloc((size_t)NIMG * KTOT * 4));
    float* sscore = (float*)(ws + alloc((size_t)NIMG * KTOT * 4));
    int* svalid = (int*)(ws + alloc((size_t)NIMG * KTOT * 4));
    float* cx1 = (float*)(ws + alloc((size_t)NIMG * SLOTCAP * 4));
    float* cy1 = (float*)(ws + alloc((size_t)NIMG * SLOTCAP * 4));
    float* cx2 = (float*)(ws + alloc((size_t)NIMG * SLOTCAP * 4));
    float* cy2 = (float*)(ws + alloc((size_t)NIMG * SLOTCAP * 4));
    float* car = (float*)(ws + alloc((size_t)NIMG * SLOTCAP * 4));
    unsigned long long* ckey = (unsigned long long*)(ws + alloc((size_t)NIMG * SLOTCAP * 8));
    int* cslot = (int*)(ws + alloc((size_t)NIMG * SLOTCAP * 4));
    int* cm = (int*)(ws + alloc((size_t)NIMG * 5 * 4));
    unsigned long long* maskBuf = (unsigned long long*)(ws + alloc((size_t)NIMG * 68056ULL * 8));
    unsigned long long* keptKey = (unsigned long long*)(ws + alloc((size_t)NIMG * KTOT * 8));
    int* keptSlot = (int*)(ws + alloc((size_t)NIMG * KTOT * 4));
    int* keptCnt = (int*)(ws + alloc((size_t)NIMG * 5 * 4));

    topk_kernel<<<dim3(NIMG * 5), dim3(1024), 0, stream>>>(obj, selIdx, selLogit);
    decode_kernel<<<dim3((KTOT + 255) / 256, NIMG), dim3(256), 0, stream>>>(
        deltas, anchors, selIdx, selLogit, sx1, sy1, sx2, sy2, sscore, svalid);
    compact_kernel<<<dim3(NIMG * 5), dim3(1024), 0, stream>>>(
        sx1, sy1, sx2, sy2, sscore, svalid, cx1, cy1, cx2, cy2, car, ckey, cslot, cm);
    mask_kernel<<<dim3(17, NIMG * 5), dim3(512), 0, stream>>>(cx1, cy1, cx2, cy2, car, cm,
                                                              maskBuf);
    scan_kernel<<<dim3(NIMG * 5), dim3(1024), 0, stream>>>(maskBuf, ckey, cslot, cm, keptKey,
                                                           keptSlot, keptCnt);
    out_kernel<<<dim3(NIMG), dim3(1024), 0, stream>>>(sx1, sy1, sx2, sy2, sscore, keptKey,
                                                      keptSlot, keptCnt, out);
}

// Round 3
// 315.155 us; speedup vs baseline: 3.1902x; 1.1391x over previous
//
#include <hip/hip_runtime.h>
#include <stdint.h>

#define KTOT 4507
#define POSTN 1000
#define ATOT 159882
#define NIMG 4
#define CAND_CAP 4096
#define SLOTCAP 5000  // per-image compact capacity (koff spacing = lvl*1000)

// ---------- helpers ----------

__device__ inline unsigned fmono(float f) {
    unsigned u = __float_as_uint(f);
    return (u & 0x80000000u) ? ~u : (u | 0x80000000u);
}
__device__ inline float fmono_inv(unsigned u) {
    unsigned b = (u & 0x80000000u) ? (u ^ 0x80000000u) : ~u;
    return __uint_as_float(b);
}

// exclusive prefix over a 1024-thread block; warpSums = LDS int[>=16]; call uniformly.
// NOTE: caller must __syncthreads() before reusing warpSums in a later call.
__device__ inline int blockExclScan(int v, int* warpSums) {
    int tid = threadIdx.x;
    int lane = tid & 63, wid = tid >> 6;
    int x = v;
#pragma unroll
    for (int d = 1; d < 64; d <<= 1) {
        int y = __shfl_up(x, d);
        if (lane >= d) x += y;
    }
    if (lane == 63) warpSums[wid] = x;
    __syncthreads();
    if (wid == 0) {
        int s = (lane < 16) ? warpSums[lane] : 0;
#pragma unroll
        for (int d = 1; d < 16; d <<= 1) {
            int y = __shfl_up(s, d);
            if (lane >= d) s += y;
        }
        if (lane < 16) warpSums[lane] = s;
    }
    __syncthreads();
    int wpre = (wid == 0) ? 0 : warpSums[wid - 1];
    return wpre + (x - v);
}

// ---------- stage A: per-(img,level) top-k, emitted in (logit desc, idx asc) order ----------

__global__ __launch_bounds__(1024) void topk_kernel(const float* __restrict__ obj,
                                                    int* __restrict__ selIdx,
                                                    float* __restrict__ selLogit) {
    __shared__ unsigned hist[4096];
    __shared__ unsigned long long cand[CAND_CAP];
    __shared__ int s_misc[32];
    __shared__ int s_cnt, s_bstar;

    const int lvlOff[5] = {0, 120000, 150000, 157500, 159375};
    const int lvlN[5]   = {120000, 30000, 7500, 1875, 507};

    int img = blockIdx.x / 5, lvl = blockIdx.x % 5;
    int n = lvlN[lvl];
    int k = (lvl == 4) ? 507 : 1000;
    int koff = lvl * 1000;
    const float* src = obj + (size_t)img * ATOT + lvlOff[lvl];
    int tid = threadIdx.x;
    int lane = tid & 63;

    for (int i = tid; i < 4096; i += 1024) hist[i] = 0u;
    if (tid == 0) s_cnt = 0;
    __syncthreads();

    // pass 1: histogram, 8-way batched loads for latency hiding
    for (int base = tid; base < n; base += 8192) {
        float v[8];
        int ok[8];
#pragma unroll
        for (int u = 0; u < 8; u++) {
            int ix = base + (u << 10);
            ok[u] = ix < n;
            v[u] = src[ok[u] ? ix : 0];
        }
#pragma unroll
        for (int u = 0; u < 8; u++)
            if (ok[u]) atomicAdd(&hist[fmono(v[u]) >> 20], 1u);
    }
    __syncthreads();

    unsigned c0 = hist[4 * tid + 0], c1 = hist[4 * tid + 1];
    unsigned c2 = hist[4 * tid + 2], c3 = hist[4 * tid + 3];
    int mysum = (int)(c0 + c1 + c2 + c3);
    int excl = blockExclScan(mysum, s_misc);
    int target = n - k;
    {
        int P = excl;
        if ((int)c0 > 0 && P <= target && target < P + (int)c0) s_bstar = 4 * tid + 0;
        P += (int)c0;
        if ((int)c1 > 0 && P <= target && target < P + (int)c1) s_bstar = 4 * tid + 1;
        P += (int)c1;
        if ((int)c2 > 0 && P <= target && target < P + (int)c2) s_bstar = 4 * tid + 2;
        P += (int)c2;
        if ((int)c3 > 0 && P <= target && target < P + (int)c3) s_bstar = 4 * tid + 3;
    }
    __syncthreads();
    int bstar = s_bstar;

    // pass 2: gather candidates, 8-way batched + wave-aggregated LDS atomic
    for (int base = tid; base < n; base += 8192) {
        float v[8];
        int ok[8];
#pragma unroll
        for (int u = 0; u < 8; u++) {
            int ix = base + (u << 10);
            ok[u] = ix < n;
            v[u] = src[ok[u] ? ix : 0];
        }
#pragma unroll
        for (int u = 0; u < 8; u++) {
            int ix = base + (u << 10);
            unsigned key = fmono(v[u]);
            bool s = ok[u] && ((int)(key >> 20) >= bstar);
            unsigned long long mk = __ballot(s);
            if (mk) {
                int pre = __popcll(mk & ((1ULL << lane) - 1ULL));
                int ldr = __builtin_ctzll(mk);
                int basew = 0;
                if (lane == ldr) basew = atomicAdd(&s_cnt, __popcll(mk));
                basew = __shfl(basew, ldr);
                if (s) {
                    int pos = basew + pre;
                    if (pos < CAND_CAP)
                        cand[pos] =
                            ((unsigned long long)key << 32) | (unsigned)(~(unsigned)ix);
                }
            }
        }
    }
    __syncthreads();
    int m = s_cnt; if (m > CAND_CAP) m = CAND_CAP;
    for (int i = tid; i < CAND_CAP; i += 1024)
        if (i >= m) cand[i] = 0ULL;
    __syncthreads();

    // bitonic ascending sort of CAND_CAP u64 keys
    for (unsigned kk = 2; kk <= CAND_CAP; kk <<= 1) {
        for (unsigned j = kk >> 1; j > 0; j >>= 1) {
            for (unsigned i = (unsigned)tid; i < CAND_CAP; i += 1024) {
                unsigned ixj = i ^ j;
                if (ixj > i) {
                    unsigned long long a = cand[i], b = cand[ixj];
                    bool up = ((i & kk) == 0);
                    if ((a > b) == up) { cand[i] = b; cand[ixj] = a; }
                }
            }
            __syncthreads();
        }
    }

    for (int r = tid; r < k; r += 1024) {
        unsigned long long key = cand[CAND_CAP - 1 - r];
        unsigned hi = (unsigned)(key >> 32);
        int li = (int)(~(unsigned)key);
        selIdx[(size_t)img * KTOT + koff + r] = lvlOff[lvl] + li;
        selLogit[(size_t)img * KTOT + koff + r] = fmono_inv(hi);
    }
}

// ---------- stage B: decode + score + valid + per-level compaction (fused) ----------

__global__ __launch_bounds__(1024) void decode_compact_kernel(
    const float* __restrict__ deltas, const float* __restrict__ anchors,
    const int* __restrict__ selIdx, const float* __restrict__ selLogit,
    float* __restrict__ sx1, float* __restrict__ sy1, float* __restrict__ sx2,
    float* __restrict__ sy2, float* __restrict__ sscore,
    float* __restrict__ cx1, float* __restrict__ cy1, float* __restrict__ cx2,
    float* __restrict__ cy2, float* __restrict__ car,
    unsigned long long* __restrict__ ckey, int* __restrict__ cslot, int* __restrict__ cm) {
    __shared__ int s_warp[32];
    int img = blockIdx.x / 5, lvl = blockIdx.x % 5;
    int kn = (lvl == 4) ? 507 : 1000;
    int koff = lvl * 1000;
    int tid = threadIdx.x;
    int r = tid;
    size_t o = (size_t)img * KTOT + koff + r;

    float x1 = 0.f, y1 = 0.f, x2 = 0.f, y2 = 0.f, s = 0.f;
    int valid = 0;
    if (r < kn) {
        int idx = selIdx[o];
        float logit = selLogit[o];
        float ef = (float)exp(-(double)logit);
        s = 1.0f / __fadd_rn(1.0f, ef);
        float a0 = anchors[(size_t)idx * 4 + 0], a1 = anchors[(size_t)idx * 4 + 1];
        float a2 = anchors[(size_t)idx * 4 + 2], a3 = anchors[(size_t)idx * 4 + 3];
        const float* dp = deltas + ((size_t)img * ATOT + idx) * 4;
        float dx = dp[0], dy = dp[1];
        const float BCLIP = 4.135166556742356f;  // log(1000/16)
        float dw = fminf(dp[2], BCLIP), dh = fminf(dp[3], BCLIP);
        float wa = __fsub_rn(a2, a0), ha = __fsub_rn(a3, a1);
        float cxa = __fadd_rn(a0, __fmul_rn(0.5f, wa));
        float cya = __fadd_rn(a1, __fmul_rn(0.5f, ha));
        float cx = __fadd_rn(__fmul_rn(dx, wa), cxa);
        float cy = __fadd_rn(__fmul_rn(dy, ha), cya);
        float w = __fmul_rn((float)exp((double)dw), wa);
        float h = __fmul_rn((float)exp((double)dh), ha);
        x1 = __fsub_rn(cx, __fmul_rn(0.5f, w));
        y1 = __fsub_rn(cy, __fmul_rn(0.5f, h));
        x2 = __fadd_rn(cx, __fmul_rn(0.5f, w));
        y2 = __fadd_rn(cy, __fmul_rn(0.5f, h));
        x1 = fminf(fmaxf(x1, 0.0f), 800.0f);
        y1 = fminf(fmaxf(y1, 0.0f), 800.0f);
        x2 = fminf(fmaxf(x2, 0.0f), 800.0f);
        y2 = fminf(fmaxf(y2, 0.0f), 800.0f);
        valid = (__fsub_rn(x2, x1) >= 0.001f) && (__fsub_rn(y2, y1) >= 0.001f) && (s >= 0.0f);
        sx1[o] = x1; sy1[o] = y1; sx2[o] = x2; sy2[o] = y2; sscore[o] = s;
    }

    int pos = blockExclScan(valid, s_warp);
    if (valid) {
        float lf = 1000.0f * (float)lvl;
        size_t cb = (size_t)img * SLOTCAP + koff + pos;
        float ox1 = __fadd_rn(x1, lf);
        float oy1 = __fadd_rn(y1, lf);
        float ox2 = __fadd_rn(x2, lf);
        float oy2 = __fadd_rn(y2, lf);
        cx1[cb] = ox1; cy1[cb] = oy1; cx2[cb] = ox2; cy2[cb] = oy2;
        car[cb] = __fmul_rn(__fsub_rn(ox2, ox1), __fsub_rn(oy2, oy1));
        int p = koff + r;
        ckey[cb] = ((unsigned long long)fmono(s) << 32) | (unsigned)(~(unsigned)p);
        cslot[cb] = p;
    }
    if (tid == 1023) cm[img * 5 + lvl] = pos + valid;
}

// ---------- stage C: suppression-mask build, one wave per 64x64 tile, ballot form ----------

__global__ __launch_bounds__(512) void mask_kernel(
    const float* __restrict__ cx1, const float* __restrict__ cy1,
    const float* __restrict__ cx2, const float* __restrict__ cy2,
    const float* __restrict__ car, const int* __restrict__ cm,
    unsigned long long* __restrict__ maskBuf) {
    __shared__ float lx1[1000], ly1[1000], lx2[1000], ly2[1000], lar[1000];
    int iq = blockIdx.y;
    int img = iq / 5, lvl = iq % 5;
    int m = cm[img * 5 + lvl];
    int W = (m + 63) >> 6;
    int T = (W * (W + 1)) >> 1;  // one task per lower-triangular 64x64 tile (w, c<=w)
    int tbase = blockIdx.x * 8;
    if (tbase >= T) return;

    size_t cb0 = (size_t)img * SLOTCAP + lvl * 1000;
    for (int q = threadIdx.x; q < m; q += 512) {
        lx1[q] = cx1[cb0 + q]; ly1[q] = cy1[cb0 + q];
        lx2[q] = cx2[cb0 + q]; ly2[q] = cy2[cb0 + q];
        lar[q] = car[cb0 + q];
    }
    __syncthreads();

    int wv = threadIdx.x >> 6, lane = threadIdx.x & 63;
    int t = tbase + wv;
    if (t >= T) return;
    int w = (int)((sqrtf(8.0f * (float)t + 1.0f) - 1.0f) * 0.5f);
    while (((w + 1) * (w + 2)) / 2 <= t) w++;
    while ((w * (w + 1)) / 2 > t) w--;
    int c = t - ((w * (w + 1)) >> 1);

    size_t mOff = (size_t)img * 68056 + (size_t)lvl * 16000;
    int Wa = (lvl == 4) ? 8 : 16;
    unsigned long long* M = maskBuf + mOff;

    int j = (w << 6) + lane;
    bool jv = j < m;
    float jx1 = jv ? lx1[j] : 0.f, jy1 = jv ? ly1[j] : 0.f;
    float jx2 = jv ? lx2[j] : 0.f, jy2 = jv ? ly2[j] : 0.f;
    float jar = jv ? lar[j] : 0.f;

    unsigned long long myword = 0ULL;
    int i0 = c << 6, i1 = min(i0 + 64, m);
    for (int i = i0; i < i1; i++) {
        float ix1 = lx1[i], iy1 = ly1[i], ix2 = lx2[i], iy2 = ly2[i], iar = lar[i];
        float ltx = fmaxf(ix1, jx1);
        float lty = fmaxf(iy1, jy1);
        float rbx = fminf(ix2, jx2);
        float rby = fminf(iy2, jy2);
        float wq = fmaxf(__fsub_rn(rbx, ltx), 0.0f);
        float hq = fmaxf(__fsub_rn(rby, lty), 0.0f);
        float inter = __fmul_rn(wq, hq);
        float uni = __fsub_rn(__fadd_rn(iar, jar), inter);
        float iou = inter / uni;  // keep IEEE div: decisions must match reference exactly
        bool bit = jv && (j > i) && (iou > 0.7f);
        unsigned long long bal = __ballot(bit);
        if (lane == (i & 63)) myword = bal;
    }
    int irow = i0 + lane;
    if (irow < i1) M[(size_t)irow * Wa + w] = myword;
}

// ---------- stage D (fused): per-level ballot-scan NMS + global rank + output ----------

__global__ __launch_bounds__(1024) void scanout_kernel(
    const float* __restrict__ sx1, const float* __restrict__ sy1,
    const float* __restrict__ sx2, const float* __restrict__ sy2,
    const float* __restrict__ sscore,
    const unsigned long long* __restrict__ ckey, const int* __restrict__ cslot,
    const int* __restrict__ cm, const unsigned long long* __restrict__ maskBuf,
    float* __restrict__ out) {
    __shared__ int lkeep[5][1024];
    __shared__ unsigned long long kkey[SLOTCAP];
    __shared__ int kslot[SLOTCAP];
    __shared__ int s_warp[32];
    __shared__ int s_cnt[5];

    int img = blockIdx.x, tid = threadIdx.x;
    int wv = tid >> 6, lane = tid & 63;

    // waves 0..4 each run their level's sequential greedy scan (ballot broadcast,
    // no LDS/bpermute in the dependency chain)
    if (wv < 5) {
        int lvl = wv;
        int m = cm[img * 5 + lvl];
        int W = (m + 63) >> 6;
        int Wa = (lvl == 4) ? 8 : 16;
        const unsigned long long* M = maskBuf + (size_t)img * 68056 + (size_t)lvl * 16000;
        bool own = lane < W;
        int mlim = min(m, (lane + 1) << 6);  // rows >= this have zero bits in word `lane`
        const unsigned long long* Mr = M + lane;
        unsigned long long remv = 0ULL;
        unsigned long long pf[16];
#pragma unroll
        for (int r2 = 0; r2 < 16; r2++)
            pf[r2] = (own && r2 < mlim) ? Mr[(size_t)r2 * Wa] : 0ULL;
        int nch = (m + 15) >> 4;
        for (int ch = 0; ch < nch; ch++) {
            unsigned long long cur[16];
#pragma unroll
            for (int r2 = 0; r2 < 16; r2++) cur[r2] = pf[r2];
            int nb = (ch + 1) << 4;
#pragma unroll
            for (int r2 = 0; r2 < 16; r2++) {
                int i2 = nb + r2;
                pf[r2] = (own && i2 < mlim) ? Mr[(size_t)i2 * Wa] : 0ULL;
            }
#pragma unroll
            for (int r2 = 0; r2 < 16; r2++) {
                int i = (ch << 4) + r2;
                if (i < m) {
                    bool mine = ((remv >> (i & 63)) & 1ULL) != 0ULL;
                    unsigned long long bal = __ballot(mine);
                    bool alive = ((bal >> (i >> 6)) & 1ULL) == 0ULL;
                    if (alive) remv |= cur[r2];
                    if (lane == 0) lkeep[lvl][i] = alive ? 1 : 0;
                }
            }
        }
    }
    __syncthreads();

    // per-level stable compaction of keeps into LDS kept lists
    for (int lvl = 0; lvl < 5; lvl++) {
        int m = cm[img * 5 + lvl];
        int koff = lvl * 1000;
        int flag = (tid < m) ? lkeep[lvl][tid] : 0;
        int pos = blockExclScan(flag, s_warp);
        if (flag) {
            size_t cb = (size_t)img * SLOTCAP + koff + tid;
            kkey[koff + pos] = ckey[cb];
            kslot[koff + pos] = cslot[cb];
        }
        if (tid == 1023) s_cnt[lvl] = pos + flag;
        __syncthreads();
    }

    int tK = s_cnt[0] + s_cnt[1] + s_cnt[2] + s_cnt[3] + s_cnt[4];

    // global rank via 5-list binary search; write output rows
    for (int lvl = 0; lvl < 5; lvl++) {
        int Kc = s_cnt[lvl];
        int koff = lvl * 1000;
        for (int q = tid; q < Kc; q += 1024) {
            unsigned long long key = kkey[koff + q];
            int rank = q;  // own list: q keys strictly greater (desc, distinct)
#pragma unroll
            for (int ol = 0; ol < 5; ol++) {
                if (ol == lvl) continue;
                int lo = 0, hi = s_cnt[ol], base = ol * 1000;
                while (lo < hi) {
                    int mid = (lo + hi) >> 1;
                    if (kkey[base + mid] > key) lo = mid + 1; else hi = mid;
                }
                rank += lo;
            }
            if (rank < POSTN) {
                int slot = kslot[koff + q];
                size_t o = (size_t)img * KTOT + slot;
                float* dst = out + ((size_t)img * POSTN + rank) * 5;
                dst[0] = sx1[o]; dst[1] = sy1[o]; dst[2] = sx2[o]; dst[3] = sy2[o];
                dst[4] = sscore[o];
            }
        }
    }

    int z0 = tK < POSTN ? tK : POSTN;
    int nz = (POSTN - z0) * 5;
    float* ob = out + (size_t)img * POSTN * 5 + (size_t)z0 * 5;
    for (int u = tid; u < nz; u += 1024) ob[u] = 0.f;
}

// ---------- host ----------

extern "C" void kernel_launch(void* const* d_in, const int* in_sizes, int n_in,
                              void* d_out, int out_size, void* d_ws, size_t ws_size,
                              hipStream_t stream) {
    const float* obj = (const float*)d_in[0];
    const float* deltas = (const float*)d_in[1];
    const float* anchors = (const float*)d_in[2];
    float* out = (float*)d_out;

    char* ws = (char*)d_ws;
    size_t off = 0;
    auto alloc = [&](size_t bytes) {
        size_t o = off;
        off += (bytes + 255) & ~(size_t)255;
        return o;
    };
    int* selIdx = (int*)(ws + alloc((size_t)NIMG * KTOT * 4));
    float* selLogit = (float*)(ws + alloc((size_t)NIMG * KTOT * 4));
    float* sx1 = (float*)(ws + alloc((size_t)NIMG * KTOT * 4));
    float* sy1 = (float*)(ws + alloc((size_t)NIMG * KTOT * 4));
    float* sx2 = (float*)(ws + alloc((size_t)NIMG * KTOT * 4));
    float* sy2 = (float*)(ws + alloc((size_t)NIMG * KTOT * 4));
    float* sscore = (float*)(ws + alloc((size_t)NIMG * KTOT * 4));
    float* cx1 = (float*)(ws + alloc((size_t)NIMG * SLOTCAP * 4));
    float* cy1 = (float*)(ws + alloc((size_t)NIMG * SLOTCAP * 4));
    float* cx2 = (float*)(ws + alloc((size_t)NIMG * SLOTCAP * 4));
    float* cy2 = (float*)(ws + alloc((size_t)NIMG * SLOTCAP * 4));
    float* car = (float*)(ws + alloc((size_t)NIMG * SLOTCAP * 4));
    unsigned long long* ckey = (unsigned long long*)(ws + alloc((size_t)NIMG * SLOTCAP * 8));
    int* cslot = (int*)(ws + alloc((size_t)NIMG * SLOTCAP * 4));
    int* cm = (int*)(ws + alloc((size_t)NIMG * 5 * 4));
    unsigned long long* maskBuf = (unsigned long long*)(ws + alloc((size_t)NIMG * 68056ULL * 8));

    topk_kernel<<<dim3(NIMG * 5), dim3(1024), 0, stream>>>(obj, selIdx, selLogit);
    decode_compact_kernel<<<dim3(NIMG * 5), dim3(1024), 0, stream>>>(
        deltas, anchors, selIdx, selLogit, sx1, sy1, sx2, sy2, sscore,
        cx1, cy1, cx2, cy2, car, ckey, cslot, cm);
    mask_kernel<<<dim3(17, NIMG * 5), dim3(512), 0, stream>>>(cx1, cy1, cx2, cy2, car, cm,
                                                              maskBuf);
    scanout_kernel<<<dim3(NIMG), dim3(1024), 0, stream>>>(
        sx1, sy1, sx2, sy2, sscore, ckey, cslot, cm, maskBuf, out);
}